// Round 5
// baseline (166.680 us; speedup 1.0000x reference)
//
#include <hip/hip_runtime.h>
#include <cmath>

// ---------------------------------------------------------------------------
// NeuralField: hashgrid encode (8 levels x 8 feats, smoothstep) + MLP
// 64 -> 256 -> 256 -> 256 -> 1 (ReLU x3, linear out), N = 262144 points.
// R16: deep weight prefetch. R12/R14/R15 all sit at 105-112 us, MfmaUtil
// ~31% across 16/19/32 waves/CU => NOT occupancy, NOT barriers (R15 null),
// NOT LDS/L2 throughput (R13 null). Model: K-loop weight frag comes from
// L2 (~200 cyc) with 1-step prefetch (~16 cyc MFMA issue of cover); ~5
// waves/SIMD * 16 cyc = 80 cyc cover per 200 cyc window => ~35% util --
// matches 31% at ANY occupancy. R15's VGPR_Count=36 also shows the
// compiler collapsed even the 1-deep rotation (36 regs can't hold
// wf+wn+a0/a1+b0/b1 concurrently).
// Fix: explicit distance-4 rotating weight prefetch, 5 slots (20 VGPR);
// frag kb+4 issued ~4 steps + inter-wave ahead of use => L2 latency
// covered by ILP. B-frags stay 1-deep (LDS latency, TLP-covered).
// L0 (KB=4) = full preload. Reg tally ~80 <= 85 cap, keep (512,6).
// Everything else = R15 (raw s_barrier + lgkm-only waits, in-place bufA,
// fused final, 36 KB LDS).
// Tripwires: VGPR=85+WRITE>>1MB => spill; VGPR<=48 => rotation collapsed.
// ---------------------------------------------------------------------------

#define N_LEVELS 8
#define TABLE_PAD 8192
#define TILE_M 64
#define ACT_STRIDE 264       // shorts per activation row (256 + 8 pad)

typedef __attribute__((ext_vector_type(8))) short short8;
typedef __attribute__((ext_vector_type(16))) float float16v;

// lgkm-only drain (keeps global loads in flight), compiler memory fence.
#define LGKM0() asm volatile("s_waitcnt lgkmcnt(0)" ::: "memory")
// keep LDS ops from moving across the barrier at compile time
#define CFENCE() asm volatile("" ::: "memory")

struct LevelParams {
  float scale[N_LEVELS];
  int   res[N_LEVELS];
  int   size[N_LEVELS];
};

__device__ __forceinline__ unsigned short f2bf(float f) {
  unsigned int u = __float_as_uint(f);
  u += 0x7fffu + ((u >> 16) & 1u);      // round to nearest even
  return (unsigned short)(u >> 16);
}
__device__ __forceinline__ unsigned int pack2bf(float a, float b) {
  a = a > 0.f ? a : 0.f;
  b = b > 0.f ? b : 0.f;
  return (unsigned int)f2bf(a) | ((unsigned int)f2bf(b) << 16);
}

// Pack W (K x 256 row-major f32) -> bf16 [k/16][n][k%16]: one lane's 16 B
// A-frag for 32x32x16 (feature n, k-half h8) is contiguous at n*16 + h8*8.
// Wp layout: [W0p: 4*4096][W1p: 16*4096][W2p: 16*4096] shorts.
__global__ void pack_weights_kernel(const float* __restrict__ W0,
                                    const float* __restrict__ W1,
                                    const float* __restrict__ W2,
                                    unsigned short* __restrict__ Wp) {
  int tid = blockIdx.x * blockDim.x + threadIdx.x;
  const float* src;
  int base, e;
  if (tid < 16384)        { src = W0; base = 0;     e = tid;         }
  else if (tid < 81920)   { src = W1; base = 16384; e = tid - 16384; }
  else if (tid < 147456)  { src = W2; base = 81920; e = tid - 81920; }
  else return;
  int ki = e & 15;
  int n  = (e >> 4) & 255;
  int kb = e >> 12;
  unsigned int u = __float_as_uint(src[(kb * 16 + ki) * 256 + n]);
  u += 0x7fffu + ((u >> 16) & 1u);
  Wp[base + e] = (unsigned short)(u >> 16);
}

__global__ __launch_bounds__(512, 6) void neural_field_kernel(
    const float* __restrict__ x,
    const float* __restrict__ table,
    const unsigned short* __restrict__ Wp,
    const float* __restrict__ W3,
    float* __restrict__ out,
    LevelParams P) {
  // ONE activation buffer, [point m][feature k]. Encode output in cols
  // 0..63; every layer reads what it needs, mid-layer barrier, overwrites.
  __shared__ unsigned short bufA[TILE_M * ACT_STRIDE];   // 33792 B
  __shared__ float fsum[TILE_M * 9];                     //  2304 B

  const int t  = threadIdx.x;
  const int g0 = blockIdx.x * TILE_M;

  const int lane  = t & 63;
  const int w     = t >> 6;       // 0..7
  const int l31   = lane & 31;
  const int h8    = lane >> 5;    // 0/1: k-half within a 16-k step
  const int wbase = w * 32;       // this wave's 32 OUTPUT FEATURES

  // Per-wave weight A-frag base offset (elements) in a layer's packed W.
  const int woff = (wbase + l31) * 16 + h8 * 8;

  // ------------- Phase 1: hashgrid encode, 1 level/thread -> bufA ---------
  {
    int p = t & 63;        // point within tile
    int l = t >> 6;        // level 0..7
    float2 xy = ((const float2*)x)[g0 + p];
    float scale = P.scale[l];
    int res = P.res[l], size = P.size[l];
    float posx = xy.x * scale + 0.5f;
    float posy = xy.y * scale + 0.5f;
    float pgx = floorf(posx), pgy = floorf(posy);
    float fx = posx - pgx, fy = posy - pgy;
    float wx = fx * fx * (3.0f - 2.0f * fx);
    float wy = fy * fy * (3.0f - 2.0f * fy);
    int px = (int)pgx, py = (int)pgy;
    float acc[8] = {0, 0, 0, 0, 0, 0, 0, 0};
    for (int dy = 0; dy < 2; ++dy) {
      float wyv = dy ? wy : 1.0f - wy;
      for (int dx = 0; dx < 2; ++dx) {
        float wgt = (dx ? wx : 1.0f - wx) * wyv;
        int idx = (px + dx) + (py + dy) * res;
        if (idx >= size) idx -= size;   // idx < 2*size always
        const float4* tp =
            (const float4*)(table + ((size_t)l * TABLE_PAD + idx) * 8);
        float4 t0 = tp[0], t1 = tp[1];
        acc[0] += wgt * t0.x; acc[1] += wgt * t0.y;
        acc[2] += wgt * t0.z; acc[3] += wgt * t0.w;
        acc[4] += wgt * t1.x; acc[5] += wgt * t1.y;
        acc[6] += wgt * t1.z; acc[7] += wgt * t1.w;
      }
    }
    union { unsigned short s[8]; short8 v; } u;
    for (int j = 0; j < 8; ++j) u.s[j] = f2bf(acc[j]);
    *(short8*)&bufA[p * ACT_STRIDE + l * 8] = u.v;
  }

  LGKM0();                          // encode ds_writes complete
  __builtin_amdgcn_s_barrier();
  CFENCE();

  // ---- MFMA layer (transposed, 32x32x16): D = W^T[32 x K] @ X^T[K x 64] --
  // A-frag (weights): row n = wbase+l31, k = kb*16 + h8*8 + j   (from L2).
  // B-frag (acts):    col m = pt*32+l31, k = kb*16 + h8*8 + j   (from LDS).
  // D: col m = pt*32+l31; reg 4q+r -> n = wbase + 8q + 4h8 + r.
  // Weight frags: 5-slot rotation, prefetch distance 4 (frag j in slot
  // j%5; (kb+4)%5 != kb%5 always). All indices compile-time after unroll.
  // inplace: raw barrier between last K-loop read and epilogue overwrite.
  auto run_layer = [&](const unsigned short* Wpl, int KB,
                       bool inplace, bool fuse_final) {
    float16v acc[2];
#pragma unroll
    for (int j = 0; j < 16; ++j) { acc[0][j] = 0.f; acc[1][j] = 0.f; }

    const unsigned short* ap0 = &bufA[l31 * ACT_STRIDE + h8 * 8];
    const unsigned short* ap1 = ap0 + 32 * ACT_STRIDE;
    const unsigned short* wp  = Wpl + woff;

    // Prologue: issue the 4 longest-latency loads (L2 weights) first,
    // then the first B-frag pair from LDS.
    short8 wr[5];
    wr[0] = *(const short8*)(wp);
    wr[1] = *(const short8*)(wp + 1 * 4096);
    wr[2] = (KB > 2) ? *(const short8*)(wp + 2 * 4096) : wr[0];
    wr[3] = (KB > 3) ? *(const short8*)(wp + 3 * 4096) : wr[0];
    short8 a0 = *(const short8*)(ap0);
    short8 a1 = *(const short8*)(ap1);

#pragma unroll
    for (int kb = 0; kb < KB; ++kb) {
      // prefetch weight frag kb+4 into slot (kb+4)%5 (never the slot
      // being consumed this step).
      if (kb + 4 < KB)
        wr[(kb + 4) % 5] = *(const short8*)(wp + (kb + 4) * 4096);
      // prefetch next B-frag pair (1-deep; LDS latency is TLP-covered).
      short8 b0, b1;
      if (kb + 1 < KB) {
        b0 = *(const short8*)(ap0 + (kb + 1) * 16);
        b1 = *(const short8*)(ap1 + (kb + 1) * 16);
      }
      const short8 wf = wr[kb % 5];
      acc[0] = __builtin_amdgcn_mfma_f32_32x32x16_bf16(wf, a0, acc[0],
                                                       0, 0, 0);
      acc[1] = __builtin_amdgcn_mfma_f32_32x32x16_bf16(wf, a1, acc[1],
                                                       0, 0, 0);
      if (kb + 1 < KB) { a0 = b0; a1 = b1; }
    }

    if (inplace) {
      // All waves' ds_reads are consumed by MFMAs above (compiler lgkm
      // waits precede issue); raw barrier suffices for read-before-write.
      __builtin_amdgcn_s_barrier();
      CFENCE();
    }

    if (!fuse_final) {
      // Epilogue: ReLU + bf16 pack; 4 b64 writes per pt-tile, already in
      // the next layer's [m][k-contiguous] layout.
#pragma unroll
      for (int pt = 0; pt < 2; ++pt) {
        int m = pt * 32 + l31;
#pragma unroll
        for (int q = 0; q < 4; ++q) {
          int n0 = wbase + 8 * q + 4 * h8;
          uint2 pk;
          pk.x = pack2bf(acc[pt][4 * q + 0], acc[pt][4 * q + 1]);
          pk.y = pack2bf(acc[pt][4 * q + 2], acc[pt][4 * q + 3]);
          *(uint2*)&bufA[m * ACT_STRIDE + n0] = pk;
        }
      }
    } else {
      // Fused final layer: per-lane relu-dot over this wave's 32 features
      // (16 per k-half, W3 loaded after the K-loop), combine halves via
      // shfl_xor(32), stage per-wave partials to fsum[m*9 + w].
      float part0 = 0.f, part1 = 0.f;
#pragma unroll
      for (int q = 0; q < 4; ++q) {
        float4 wv = *(const float4*)(W3 + wbase + 8 * q + 4 * h8);
        float w3v[4] = {wv.x, wv.y, wv.z, wv.w};
#pragma unroll
        for (int r = 0; r < 4; ++r) {
          float v0 = acc[0][4 * q + r]; v0 = v0 > 0.f ? v0 : 0.f;
          float v1 = acc[1][4 * q + r]; v1 = v1 > 0.f ? v1 : 0.f;
          part0 += v0 * w3v[r];
          part1 += v1 * w3v[r];
        }
      }
      part0 += __shfl_xor(part0, 32);
      part1 += __shfl_xor(part1, 32);
      float val = h8 ? part1 : part0;   // lane holds m = h8*32 + l31 = lane
      fsum[lane * 9 + w] = val;
    }
  };

  // Layer 0: reads cols 0..63 (K=64), overwrites cols 0..255 IN-PLACE
  run_layer(Wp, 4, true, false);
  LGKM0();                          // epilogue ds_writes complete
  __builtin_amdgcn_s_barrier();
  CFENCE();
  // Layer 1: bufA -> bufA IN-PLACE (raw mid-layer barrier inside)
  run_layer(Wp + 16384, 16, true, false);
  LGKM0();
  __builtin_amdgcn_s_barrier();
  CFENCE();
  // Layer 2 + final: reads bufA, writes only fsum (disjoint buffer)
  run_layer(Wp + 81920, 16, false, true);
  LGKM0();                          // fsum writes complete
  __builtin_amdgcn_s_barrier();
  CFENCE();

  // ---------------- Cross-wave reduce of fsum -> out -----------------------
  {
    int p = t >> 3;          // point within tile (0..63)
    int q = t & 7;           // wave index being summed
    float v = fsum[p * 9 + q];
    v += __shfl_xor(v, 1);
    v += __shfl_xor(v, 2);
    v += __shfl_xor(v, 4);
    if (q == 0) out[g0 + p] = v;
  }
}

extern "C" void kernel_launch(void* const* d_in, const int* in_sizes, int n_in,
                              void* d_out, int out_size, void* d_ws,
                              size_t ws_size, hipStream_t stream) {
  const float* x     = (const float*)d_in[0];
  const float* table = (const float*)d_in[1];
  const float* W0    = (const float*)d_in[2];
  const float* W1    = (const float*)d_in[3];
  const float* W2    = (const float*)d_in[4];
  const float* W3    = (const float*)d_in[5];
  float* out = (float*)d_out;
  int N = in_sizes[0] / 2;

  unsigned short* Wp = (unsigned short*)d_ws;   // 147456 bf16 = 288 KB

  // Level params, double precision to match the Python reference exactly.
  LevelParams P;
  const double c = 1.2599210739135742;
  double m = 1.0;
  for (int l = 0; l < N_LEVELS; ++l) {
    double scale_d = 16.0 * m - 1.0;
    int res = (int)std::ceil(scale_d) + 1;
    long long sz = ((long long)res * res + 7) / 8 * 8;
    if (sz > (1LL << 19)) sz = 1LL << 19;
    P.scale[l] = (float)scale_d;
    P.res[l]   = res;
    P.size[l]  = (int)sz;
    m *= c;
  }

  hipLaunchKernelGGL(pack_weights_kernel, dim3(576), dim3(256), 0, stream,
                     W0, W1, W2, Wp);
  hipLaunchKernelGGL(neural_field_kernel, dim3(N / TILE_M), dim3(512), 0,
                     stream, x, table, Wp, W3, out, P);
}

// Round 6
// 165.532 us; speedup vs baseline: 1.0069x; 1.0069x over previous
//
#include <hip/hip_runtime.h>
#include <cmath>

// ---------------------------------------------------------------------------
// NeuralField: hashgrid encode (8 levels x 8 feats, smoothstep) + MLP
// 64 -> 256 -> 256 -> 256 -> 1 (ReLU x3, linear out), N = 262144 points.
// R17: WEIGHT-STATIONARY PERSISTENT KERNEL. Four nulls (R13 redundancy,
// R14 occupancy, R15 barrier semantics, R16 reg-rotation prefetch -- the
// compiler collapsed it, VGPR=32) all point at one structural cost: every
// block re-streams 36 KB/wave of weight frags from L2 in the K-loop
// (~200 cyc latency vs ~16 cyc MFMA cover => MfmaUtil pinned ~31% at any
// occupancy). Fix: eliminate the traffic entirely. Each wave's weights =
// 36 frags x 16 B = 144 VGPRs. Persistent grid (256 blocks, 16 tiles each
// via grid-stride); wr0[4]/wr1[16]/wr2[16]/w3f[16] loaded ONCE at block
// start; K-loop = 2 ds_read_b128 + 2 MFMA per step, weight operand from
// registers (zero latency, nothing for the compiler to collapse).
// Budget: 144 W + 16 W3 + 32 acc + ~40 misc ~ 230 <= 256 (512,2).
// 8 waves/CU only -- occupancy counter WILL read ~13%; that is by design
// (2 waves/SIMD x 64 cyc MFMA issue covers ~120 cyc LDS latency).
// Everything else = R15: raw s_barrier + lgkm-only waits, in-place bufA,
// fused final layer, fsum stride-9, 36 KB LDS.
// Tripwire: WRITE_SIZE >> 2 MB => spill => demote wr2 to streamed.
// ---------------------------------------------------------------------------

#define N_LEVELS 8
#define TABLE_PAD 8192
#define TILE_M 64
#define ACT_STRIDE 264       // shorts per activation row (256 + 8 pad)

typedef __attribute__((ext_vector_type(8))) short short8;
typedef __attribute__((ext_vector_type(16))) float float16v;

// lgkm-only drain (keeps global loads in flight), compiler memory fence.
#define LGKM0() asm volatile("s_waitcnt lgkmcnt(0)" ::: "memory")
// keep LDS ops from moving across the barrier at compile time
#define CFENCE() asm volatile("" ::: "memory")

struct LevelParams {
  float scale[N_LEVELS];
  int   res[N_LEVELS];
  int   size[N_LEVELS];
};

__device__ __forceinline__ unsigned short f2bf(float f) {
  unsigned int u = __float_as_uint(f);
  u += 0x7fffu + ((u >> 16) & 1u);      // round to nearest even
  return (unsigned short)(u >> 16);
}
__device__ __forceinline__ unsigned int pack2bf(float a, float b) {
  a = a > 0.f ? a : 0.f;
  b = b > 0.f ? b : 0.f;
  return (unsigned int)f2bf(a) | ((unsigned int)f2bf(b) << 16);
}

// Pack W (K x 256 row-major f32) -> bf16 [k/16][n][k%16]: one lane's 16 B
// A-frag for 32x32x16 (feature n, k-half h8) is contiguous at n*16 + h8*8.
// Wp layout: [W0p: 4*4096][W1p: 16*4096][W2p: 16*4096] shorts.
__global__ void pack_weights_kernel(const float* __restrict__ W0,
                                    const float* __restrict__ W1,
                                    const float* __restrict__ W2,
                                    unsigned short* __restrict__ Wp) {
  int tid = blockIdx.x * blockDim.x + threadIdx.x;
  const float* src;
  int base, e;
  if (tid < 16384)        { src = W0; base = 0;     e = tid;         }
  else if (tid < 81920)   { src = W1; base = 16384; e = tid - 16384; }
  else if (tid < 147456)  { src = W2; base = 81920; e = tid - 81920; }
  else return;
  int ki = e & 15;
  int n  = (e >> 4) & 255;
  int kb = e >> 12;
  unsigned int u = __float_as_uint(src[(kb * 16 + ki) * 256 + n]);
  u += 0x7fffu + ((u >> 16) & 1u);
  Wp[base + e] = (unsigned short)(u >> 16);
}

__global__ __launch_bounds__(512, 2) void neural_field_kernel(
    const float* __restrict__ x,
    const float* __restrict__ table,
    const unsigned short* __restrict__ Wp,
    const float* __restrict__ W3,
    float* __restrict__ out,
    LevelParams P, int nTiles) {
  // ONE activation buffer, [point m][feature k]. Encode output in cols
  // 0..63; every layer reads what it needs, mid-layer barrier, overwrites.
  __shared__ unsigned short bufA[TILE_M * ACT_STRIDE];   // 33792 B
  __shared__ float fsum[TILE_M * 9];                     //  2304 B

  const int t = threadIdx.x;

  const int lane  = t & 63;
  const int w     = t >> 6;       // 0..7
  const int l31   = lane & 31;
  const int h8    = lane >> 5;    // 0/1: k-half within a 16-k step
  const int wbase = w * 32;       // this wave's 32 OUTPUT FEATURES

  // Per-wave weight A-frag base offset (elements) in a layer's packed W.
  const int woff = (wbase + l31) * 16 + h8 * 8;

  // ---------------- One-time: ALL weights -> registers --------------------
  // 36 frags x 16 B/lane = 144 VGPRs. Loaded once per persistent block;
  // first consumption is after the first encode phase (vmcnt covered).
  short8 wr0[4], wr1[16], wr2[16];
#pragma unroll
  for (int i = 0; i < 4; ++i)
    wr0[i] = *(const short8*)(Wp + woff + i * 4096);
#pragma unroll
  for (int i = 0; i < 16; ++i)
    wr1[i] = *(const short8*)(Wp + 16384 + woff + i * 4096);
#pragma unroll
  for (int i = 0; i < 16; ++i)
    wr2[i] = *(const short8*)(Wp + 81920 + woff + i * 4096);
  // Final-layer column (this wave's 32 features, 16 per k-half).
  float w3f[16];
#pragma unroll
  for (int q = 0; q < 4; ++q) {
    float4 wv = *(const float4*)(W3 + wbase + 8 * q + 4 * h8);
    w3f[4 * q + 0] = wv.x; w3f[4 * q + 1] = wv.y;
    w3f[4 * q + 2] = wv.z; w3f[4 * q + 3] = wv.w;
  }

  // ---- MFMA layer (transposed, 32x32x16): D = W^T[32 x K] @ X^T[K x 64] --
  // A-frag (weights): row n = wbase+l31, k = kb*16 + h8*8 + j  (REGISTERS).
  // B-frag (acts):    col m = pt*32+l31, k = kb*16 + h8*8 + j  (from LDS).
  // D: col m = pt*32+l31; reg 4q+r -> n = wbase + 8q + 4h8 + r.
  // inplace: raw barrier between last K-loop read and epilogue overwrite.
  auto run_layer = [&](const short8* wfr, int KB,
                       bool inplace, bool fuse_final) {
    float16v acc[2];
#pragma unroll
    for (int j = 0; j < 16; ++j) { acc[0][j] = 0.f; acc[1][j] = 0.f; }

    const unsigned short* ap0 = &bufA[l31 * ACT_STRIDE + h8 * 8];
    const unsigned short* ap1 = ap0 + 32 * ACT_STRIDE;

    short8 a0 = *(const short8*)(ap0);
    short8 a1 = *(const short8*)(ap1);

#pragma unroll
    for (int kb = 0; kb < KB; ++kb) {
      short8 b0, b1;
      if (kb + 1 < KB) {            // 1-deep B prefetch (LDS, TLP-covered)
        b0 = *(const short8*)(ap0 + (kb + 1) * 16);
        b1 = *(const short8*)(ap1 + (kb + 1) * 16);
      }
      acc[0] = __builtin_amdgcn_mfma_f32_32x32x16_bf16(wfr[kb], a0, acc[0],
                                                       0, 0, 0);
      acc[1] = __builtin_amdgcn_mfma_f32_32x32x16_bf16(wfr[kb], a1, acc[1],
                                                       0, 0, 0);
      if (kb + 1 < KB) { a0 = b0; a1 = b1; }
    }

    if (inplace) {
      // All waves' ds_reads are consumed by MFMAs above (compiler lgkm
      // waits precede issue); raw barrier suffices for read-before-write.
      __builtin_amdgcn_s_barrier();
      CFENCE();
    }

    if (!fuse_final) {
      // Epilogue: ReLU + bf16 pack; 4 b64 writes per pt-tile, already in
      // the next layer's [m][k-contiguous] layout.
#pragma unroll
      for (int pt = 0; pt < 2; ++pt) {
        int m = pt * 32 + l31;
#pragma unroll
        for (int q = 0; q < 4; ++q) {
          int n0 = wbase + 8 * q + 4 * h8;
          uint2 pk;
          pk.x = pack2bf(acc[pt][4 * q + 0], acc[pt][4 * q + 1]);
          pk.y = pack2bf(acc[pt][4 * q + 2], acc[pt][4 * q + 3]);
          *(uint2*)&bufA[m * ACT_STRIDE + n0] = pk;
        }
      }
    } else {
      // Fused final layer: per-lane relu-dot over this wave's 32 features
      // (16 per k-half, w3f resident), combine halves via shfl_xor(32),
      // stage per-wave partials to fsum[m*9 + w].
      float part0 = 0.f, part1 = 0.f;
#pragma unroll
      for (int j = 0; j < 16; ++j) {
        float v0 = acc[0][j]; v0 = v0 > 0.f ? v0 : 0.f;
        float v1 = acc[1][j]; v1 = v1 > 0.f ? v1 : 0.f;
        part0 += v0 * w3f[j];
        part1 += v1 * w3f[j];
      }
      part0 += __shfl_xor(part0, 32);
      part1 += __shfl_xor(part1, 32);
      float val = h8 ? part1 : part0;   // lane holds m = h8*32 + l31 = lane
      fsum[lane * 9 + w] = val;
    }
  };

  // ---------------- Persistent tile loop ----------------------------------
  for (int tile = blockIdx.x; tile < nTiles; tile += gridDim.x) {
    const int g0 = tile * TILE_M;

    // ----------- Phase 1: hashgrid encode, 1 level/thread -> bufA ---------
    {
      int p = t & 63;        // point within tile
      int l = t >> 6;        // level 0..7
      float2 xy = ((const float2*)x)[g0 + p];
      float scale = P.scale[l];
      int res = P.res[l], size = P.size[l];
      float posx = xy.x * scale + 0.5f;
      float posy = xy.y * scale + 0.5f;
      float pgx = floorf(posx), pgy = floorf(posy);
      float fx = posx - pgx, fy = posy - pgy;
      float wx = fx * fx * (3.0f - 2.0f * fx);
      float wy = fy * fy * (3.0f - 2.0f * fy);
      int px = (int)pgx, py = (int)pgy;
      float acc[8] = {0, 0, 0, 0, 0, 0, 0, 0};
      for (int dy = 0; dy < 2; ++dy) {
        float wyv = dy ? wy : 1.0f - wy;
        for (int dx = 0; dx < 2; ++dx) {
          float wgt = (dx ? wx : 1.0f - wx) * wyv;
          int idx = (px + dx) + (py + dy) * res;
          if (idx >= size) idx -= size;   // idx < 2*size always
          const float4* tp =
              (const float4*)(table + ((size_t)l * TABLE_PAD + idx) * 8);
          float4 t0 = tp[0], t1 = tp[1];
          acc[0] += wgt * t0.x; acc[1] += wgt * t0.y;
          acc[2] += wgt * t0.z; acc[3] += wgt * t0.w;
          acc[4] += wgt * t1.x; acc[5] += wgt * t1.y;
          acc[6] += wgt * t1.z; acc[7] += wgt * t1.w;
        }
      }
      union { unsigned short s[8]; short8 v; } u;
      for (int j = 0; j < 8; ++j) u.s[j] = f2bf(acc[j]);
      *(short8*)&bufA[p * ACT_STRIDE + l * 8] = u.v;
    }

    LGKM0();                          // encode ds_writes complete
    __builtin_amdgcn_s_barrier();
    CFENCE();

    // Layer 0: reads cols 0..63 (K=64), overwrites cols 0..255 IN-PLACE
    run_layer(wr0, 4, true, false);
    LGKM0();                          // epilogue ds_writes complete
    __builtin_amdgcn_s_barrier();
    CFENCE();
    // Layer 1: bufA -> bufA IN-PLACE (raw mid-layer barrier inside)
    run_layer(wr1, 16, true, false);
    LGKM0();
    __builtin_amdgcn_s_barrier();
    CFENCE();
    // Layer 2 + final: reads bufA, writes only fsum (disjoint buffer)
    run_layer(wr2, 16, false, true);
    LGKM0();                          // fsum writes complete
    __builtin_amdgcn_s_barrier();
    CFENCE();

    // -------------- Cross-wave reduce of fsum -> out -----------------------
    // Next iteration's encode writes bufA (disjoint from fsum); every wave
    // passes the encode barrier only after finishing its reduce reads, and
    // the next fsum write is 4 barriers away -> no race.
    {
      int p = t >> 3;          // point within tile (0..63)
      int q = t & 7;           // wave index being summed
      float v = fsum[p * 9 + q];
      v += __shfl_xor(v, 1);
      v += __shfl_xor(v, 2);
      v += __shfl_xor(v, 4);
      if (q == 0) out[g0 + p] = v;
    }
  }
}

extern "C" void kernel_launch(void* const* d_in, const int* in_sizes, int n_in,
                              void* d_out, int out_size, void* d_ws,
                              size_t ws_size, hipStream_t stream) {
  const float* x     = (const float*)d_in[0];
  const float* table = (const float*)d_in[1];
  const float* W0    = (const float*)d_in[2];
  const float* W1    = (const float*)d_in[3];
  const float* W2    = (const float*)d_in[4];
  const float* W3    = (const float*)d_in[5];
  float* out = (float*)d_out;
  int N = in_sizes[0] / 2;

  unsigned short* Wp = (unsigned short*)d_ws;   // 147456 bf16 = 288 KB

  // Level params, double precision to match the Python reference exactly.
  LevelParams P;
  const double c = 1.2599210739135742;
  double m = 1.0;
  for (int l = 0; l < N_LEVELS; ++l) {
    double scale_d = 16.0 * m - 1.0;
    int res = (int)std::ceil(scale_d) + 1;
    long long sz = ((long long)res * res + 7) / 8 * 8;
    if (sz > (1LL << 19)) sz = 1LL << 19;
    P.scale[l] = (float)scale_d;
    P.res[l]   = res;
    P.size[l]  = (int)sz;
    m *= c;
  }

  hipLaunchKernelGGL(pack_weights_kernel, dim3(576), dim3(256), 0, stream,
                     W0, W1, W2, Wp);
  // Persistent: one block per CU; each handles nTiles/256 = 16 tiles.
  hipLaunchKernelGGL(neural_field_kernel, dim3(256), dim3(512), 0,
                     stream, x, table, Wp, W3, out, P, N / TILE_M);
}

// Round 8
// 164.127 us; speedup vs baseline: 1.0156x; 1.0086x over previous
//
#include <hip/hip_runtime.h>
#include <cmath>

// ---------------------------------------------------------------------------
// NeuralField: hashgrid encode (8 levels x 8 feats, smoothstep) + MLP
// 64 -> 256 -> 256 -> 256 -> 1 (ReLU x3, linear out), N = 262144 points.
// R18 (resubmit; R7 bench was GPUAcquisitionTimeout — never ran).
// R17 + ASM-PINNED resident weights. R17's VGPR_Count=120 proves the
// compiler REMATERIALIZED the 36 loop-invariant weight loads (144 VGPRs
// needed; no spill, WRITE=1MB) -- weight-stationarity was never tested,
// R17 degenerated to "R15 at 1 block/CU" (MfmaUtil 26, 121 us). Third
// compiler defeat (R16 rotation collapse, R17 remat). Fix per guide rule
// #17: asm volatile("" : "+v"(frag)) after each load makes the value
// asm-defined -> rematerialization impossible; only escape is spill
// (visible in WRITE_SIZE). With weights truly in VGPRs the K-loop is
// 2 ds_read_b128 + 2 MFMA per k-step: W latency gone, B latency 120 cyc
// vs 128 cyc cover (2 waves/SIMD), wall = LDS port (~46us) + encode (~7).
// Pipe inventory (VALUBusy ⊇ MfmaUtil; real VALU ~8us): LDS 47, MFMA 31,
// L2-W ~34 (eliminated by this change), VALU 8.
// Predict: VGPR 220-256, dur 60-80us, MfmaUtil 40-50, WRITE ~1MB.
// Tripwires: VGPR<200 => pin failed; WRITE>>2MB => spill (demote wr2).
// ---------------------------------------------------------------------------

#define N_LEVELS 8
#define TABLE_PAD 8192
#define TILE_M 64
#define ACT_STRIDE 264       // shorts per activation row (256 + 8 pad)

typedef __attribute__((ext_vector_type(8))) short short8;
typedef __attribute__((ext_vector_type(16))) float float16v;

// lgkm-only drain (keeps global loads in flight), compiler memory fence.
#define LGKM0() asm volatile("s_waitcnt lgkmcnt(0)" ::: "memory")
// keep LDS ops from moving across the barrier at compile time
#define CFENCE() asm volatile("" ::: "memory")

struct LevelParams {
  float scale[N_LEVELS];
  int   res[N_LEVELS];
  int   size[N_LEVELS];
};

__device__ __forceinline__ unsigned short f2bf(float f) {
  unsigned int u = __float_as_uint(f);
  u += 0x7fffu + ((u >> 16) & 1u);      // round to nearest even
  return (unsigned short)(u >> 16);
}
__device__ __forceinline__ unsigned int pack2bf(float a, float b) {
  a = a > 0.f ? a : 0.f;
  b = b > 0.f ? b : 0.f;
  return (unsigned int)f2bf(a) | ((unsigned int)f2bf(b) << 16);
}

// Pack W (K x 256 row-major f32) -> bf16 [k/16][n][k%16]: one lane's 16 B
// A-frag for 32x32x16 (feature n, k-half h8) is contiguous at n*16 + h8*8.
// Wp layout: [W0p: 4*4096][W1p: 16*4096][W2p: 16*4096] shorts.
__global__ void pack_weights_kernel(const float* __restrict__ W0,
                                    const float* __restrict__ W1,
                                    const float* __restrict__ W2,
                                    unsigned short* __restrict__ Wp) {
  int tid = blockIdx.x * blockDim.x + threadIdx.x;
  const float* src;
  int base, e;
  if (tid < 16384)        { src = W0; base = 0;     e = tid;         }
  else if (tid < 81920)   { src = W1; base = 16384; e = tid - 16384; }
  else if (tid < 147456)  { src = W2; base = 81920; e = tid - 81920; }
  else return;
  int ki = e & 15;
  int n  = (e >> 4) & 255;
  int kb = e >> 12;
  unsigned int u = __float_as_uint(src[(kb * 16 + ki) * 256 + n]);
  u += 0x7fffu + ((u >> 16) & 1u);
  Wp[base + e] = (unsigned short)(u >> 16);
}

__global__ __launch_bounds__(512, 2) void neural_field_kernel(
    const float* __restrict__ x,
    const float* __restrict__ table,
    const unsigned short* __restrict__ Wp,
    const float* __restrict__ W3,
    float* __restrict__ out,
    LevelParams P, int nTiles) {
  // ONE activation buffer, [point m][feature k]. Encode output in cols
  // 0..63; every layer reads what it needs, mid-layer barrier, overwrites.
  __shared__ unsigned short bufA[TILE_M * ACT_STRIDE];   // 33792 B
  __shared__ float fsum[TILE_M * 9];                     //  2304 B

  const int t = threadIdx.x;

  const int lane  = t & 63;
  const int w     = t >> 6;       // 0..7
  const int l31   = lane & 31;
  const int h8    = lane >> 5;    // 0/1: k-half within a 16-k step
  const int wbase = w * 32;       // this wave's 32 OUTPUT FEATURES

  // Per-wave weight A-frag base offset (elements) in a layer's packed W.
  const int woff = (wbase + l31) * 16 + h8 * 8;

  // ---------------- One-time: ALL weights -> registers --------------------
  // 36 frags x 16 B/lane = 144 VGPRs + 16 for w3f. The asm "+v" pins make
  // each value asm-defined: the compiler CANNOT rematerialize the load
  // (R17 failure mode); it can only spill, which WRITE_SIZE would expose.
  short8 wr0[4], wr1[16], wr2[16];
#pragma unroll
  for (int i = 0; i < 4; ++i)
    wr0[i] = *(const short8*)(Wp + woff + i * 4096);
#pragma unroll
  for (int i = 0; i < 16; ++i)
    wr1[i] = *(const short8*)(Wp + 16384 + woff + i * 4096);
#pragma unroll
  for (int i = 0; i < 16; ++i)
    wr2[i] = *(const short8*)(Wp + 81920 + woff + i * 4096);
  // Final-layer column (this wave's 32 features, 16 per k-half).
  float w3f[16];
#pragma unroll
  for (int q = 0; q < 4; ++q) {
    float4 wv = *(const float4*)(W3 + wbase + 8 * q + 4 * h8);
    w3f[4 * q + 0] = wv.x; w3f[4 * q + 1] = wv.y;
    w3f[4 * q + 2] = wv.z; w3f[4 * q + 3] = wv.w;
  }
  // ---- pins (guide rule #17) ----
#pragma unroll
  for (int i = 0; i < 4; ++i)  asm volatile("" : "+v"(wr0[i]));
#pragma unroll
  for (int i = 0; i < 16; ++i) asm volatile("" : "+v"(wr1[i]));
#pragma unroll
  for (int i = 0; i < 16; ++i) asm volatile("" : "+v"(wr2[i]));
#pragma unroll
  for (int i = 0; i < 16; ++i) asm volatile("" : "+v"(w3f[i]));

  // ---- MFMA layer (transposed, 32x32x16): D = W^T[32 x K] @ X^T[K x 64] --
  // A-frag (weights): row n = wbase+l31, k = kb*16 + h8*8 + j  (REGISTERS).
  // B-frag (acts):    col m = pt*32+l31, k = kb*16 + h8*8 + j  (from LDS).
  // D: col m = pt*32+l31; reg 4q+r -> n = wbase + 8q + 4h8 + r.
  // inplace: raw barrier between last K-loop read and epilogue overwrite.
  auto run_layer = [&](const short8* wfr, int KB,
                       bool inplace, bool fuse_final) {
    float16v acc[2];
#pragma unroll
    for (int j = 0; j < 16; ++j) { acc[0][j] = 0.f; acc[1][j] = 0.f; }

    const unsigned short* ap0 = &bufA[l31 * ACT_STRIDE + h8 * 8];
    const unsigned short* ap1 = ap0 + 32 * ACT_STRIDE;

    short8 a0 = *(const short8*)(ap0);
    short8 a1 = *(const short8*)(ap1);

#pragma unroll
    for (int kb = 0; kb < KB; ++kb) {
      short8 b0, b1;
      if (kb + 1 < KB) {            // 1-deep B prefetch (LDS, TLP-covered)
        b0 = *(const short8*)(ap0 + (kb + 1) * 16);
        b1 = *(const short8*)(ap1 + (kb + 1) * 16);
      }
      acc[0] = __builtin_amdgcn_mfma_f32_32x32x16_bf16(wfr[kb], a0, acc[0],
                                                       0, 0, 0);
      acc[1] = __builtin_amdgcn_mfma_f32_32x32x16_bf16(wfr[kb], a1, acc[1],
                                                       0, 0, 0);
      if (kb + 1 < KB) { a0 = b0; a1 = b1; }
    }

    if (inplace) {
      // All waves' ds_reads are consumed by MFMAs above (compiler lgkm
      // waits precede issue); raw barrier suffices for read-before-write.
      __builtin_amdgcn_s_barrier();
      CFENCE();
    }

    if (!fuse_final) {
      // Epilogue: ReLU + bf16 pack; 4 b64 writes per pt-tile, already in
      // the next layer's [m][k-contiguous] layout.
#pragma unroll
      for (int pt = 0; pt < 2; ++pt) {
        int m = pt * 32 + l31;
#pragma unroll
        for (int q = 0; q < 4; ++q) {
          int n0 = wbase + 8 * q + 4 * h8;
          uint2 pk;
          pk.x = pack2bf(acc[pt][4 * q + 0], acc[pt][4 * q + 1]);
          pk.y = pack2bf(acc[pt][4 * q + 2], acc[pt][4 * q + 3]);
          *(uint2*)&bufA[m * ACT_STRIDE + n0] = pk;
        }
      }
    } else {
      // Fused final layer: per-lane relu-dot over this wave's 32 features
      // (16 per k-half, w3f resident), combine halves via shfl_xor(32),
      // stage per-wave partials to fsum[m*9 + w].
      float part0 = 0.f, part1 = 0.f;
#pragma unroll
      for (int j = 0; j < 16; ++j) {
        float v0 = acc[0][j]; v0 = v0 > 0.f ? v0 : 0.f;
        float v1 = acc[1][j]; v1 = v1 > 0.f ? v1 : 0.f;
        part0 += v0 * w3f[j];
        part1 += v1 * w3f[j];
      }
      part0 += __shfl_xor(part0, 32);
      part1 += __shfl_xor(part1, 32);
      float val = h8 ? part1 : part0;   // lane holds m = h8*32 + l31 = lane
      fsum[lane * 9 + w] = val;
    }
  };

  // ---------------- Persistent tile loop ----------------------------------
  for (int tile = blockIdx.x; tile < nTiles; tile += gridDim.x) {
    const int g0 = tile * TILE_M;

    // ----------- Phase 1: hashgrid encode, 1 level/thread -> bufA ---------
    {
      int p = t & 63;        // point within tile
      int l = t >> 6;        // level 0..7
      float2 xy = ((const float2*)x)[g0 + p];
      float scale = P.scale[l];
      int res = P.res[l], size = P.size[l];
      float posx = xy.x * scale + 0.5f;
      float posy = xy.y * scale + 0.5f;
      float pgx = floorf(posx), pgy = floorf(posy);
      float fx = posx - pgx, fy = posy - pgy;
      float wx = fx * fx * (3.0f - 2.0f * fx);
      float wy = fy * fy * (3.0f - 2.0f * fy);
      int px = (int)pgx, py = (int)pgy;
      float acc[8] = {0, 0, 0, 0, 0, 0, 0, 0};
      for (int dy = 0; dy < 2; ++dy) {
        float wyv = dy ? wy : 1.0f - wy;
        for (int dx = 0; dx < 2; ++dx) {
          float wgt = (dx ? wx : 1.0f - wx) * wyv;
          int idx = (px + dx) + (py + dy) * res;
          if (idx >= size) idx -= size;   // idx < 2*size always
          const float4* tp =
              (const float4*)(table + ((size_t)l * TABLE_PAD + idx) * 8);
          float4 t0 = tp[0], t1 = tp[1];
          acc[0] += wgt * t0.x; acc[1] += wgt * t0.y;
          acc[2] += wgt * t0.z; acc[3] += wgt * t0.w;
          acc[4] += wgt * t1.x; acc[5] += wgt * t1.y;
          acc[6] += wgt * t1.z; acc[7] += wgt * t1.w;
        }
      }
      union { unsigned short s[8]; short8 v; } u;
      for (int j = 0; j < 8; ++j) u.s[j] = f2bf(acc[j]);
      *(short8*)&bufA[p * ACT_STRIDE + l * 8] = u.v;
    }

    LGKM0();                          // encode ds_writes complete
    __builtin_amdgcn_s_barrier();
    CFENCE();

    // Layer 0: reads cols 0..63 (K=64), overwrites cols 0..255 IN-PLACE
    run_layer(wr0, 4, true, false);
    LGKM0();                          // epilogue ds_writes complete
    __builtin_amdgcn_s_barrier();
    CFENCE();
    // Layer 1: bufA -> bufA IN-PLACE (raw mid-layer barrier inside)
    run_layer(wr1, 16, true, false);
    LGKM0();
    __builtin_amdgcn_s_barrier();
    CFENCE();
    // Layer 2 + final: reads bufA, writes only fsum (disjoint buffer)
    run_layer(wr2, 16, false, true);
    LGKM0();                          // fsum writes complete
    __builtin_amdgcn_s_barrier();
    CFENCE();

    // -------------- Cross-wave reduce of fsum -> out -----------------------
    // Next iteration's encode writes bufA (disjoint from fsum); every wave
    // passes the encode barrier only after finishing its reduce reads, and
    // the next fsum write is 4 barriers away -> no race.
    {
      int p = t >> 3;          // point within tile (0..63)
      int q = t & 7;           // wave index being summed
      float v = fsum[p * 9 + q];
      v += __shfl_xor(v, 1);
      v += __shfl_xor(v, 2);
      v += __shfl_xor(v, 4);
      if (q == 0) out[g0 + p] = v;
    }
  }
}

extern "C" void kernel_launch(void* const* d_in, const int* in_sizes, int n_in,
                              void* d_out, int out_size, void* d_ws,
                              size_t ws_size, hipStream_t stream) {
  const float* x     = (const float*)d_in[0];
  const float* table = (const float*)d_in[1];
  const float* W0    = (const float*)d_in[2];
  const float* W1    = (const float*)d_in[3];
  const float* W2    = (const float*)d_in[4];
  const float* W3    = (const float*)d_in[5];
  float* out = (float*)d_out;
  int N = in_sizes[0] / 2;

  unsigned short* Wp = (unsigned short*)d_ws;   // 147456 bf16 = 288 KB

  // Level params, double precision to match the Python reference exactly.
  LevelParams P;
  const double c = 1.2599210739135742;
  double m = 1.0;
  for (int l = 0; l < N_LEVELS; ++l) {
    double scale_d = 16.0 * m - 1.0;
    int res = (int)std::ceil(scale_d) + 1;
    long long sz = ((long long)res * res + 7) / 8 * 8;
    if (sz > (1LL << 19)) sz = 1LL << 19;
    P.scale[l] = (float)scale_d;
    P.res[l]   = res;
    P.size[l]  = (int)sz;
    m *= c;
  }

  hipLaunchKernelGGL(pack_weights_kernel, dim3(576), dim3(256), 0, stream,
                     W0, W1, W2, Wp);
  // Persistent: one block per CU; each handles nTiles/256 = 16 tiles.
  hipLaunchKernelGGL(neural_field_kernel, dim3(256), dim3(512), 0,
                     stream, x, table, Wp, W3, out, P, N / TILE_M);
}